// Round 15
// baseline (1338.265 us; speedup 1.0000x reference)
//
#include <hip/hip_runtime.h>

// ---------------------------------------------------------------------------
// MoE forward: gating MLP + 8 dense experts + gate-weighted combine.
// r15 = r14 (32-MFMA phases) with CORRECTED stage/vmcnt ledger. True read
// sets per phase (2M wave split): PhA reads A{q0,q2}+B, PhB reads A{q1,q3}.
// Stage slots: PhA0->A(1){q1,q3}(t+1); PhB0->A(0){q0,q2}+B(0)(t+2);
// PhA1->A(0){q1,q3}(t+2); PhB1->A(1){q0,q2}+B(1)(t+3). Every overwrite is
// >=1 tail-barrier after the region's last read; per-phase vmcnt(8)/(6)
// leaves exactly the loads newer than the batch the next phase needs.
// ---------------------------------------------------------------------------

#define DI __device__ __forceinline__

typedef _Float16 f16;
typedef _Float16 f16x8 __attribute__((ext_vector_type(8)));
typedef float f32x4 __attribute__((ext_vector_type(4)));

constexpr int BSZ  = 8192;
constexpr int IND  = 1024;
constexpr int HID  = 4096;
constexpr int OUTD = 1024;
constexpr int NE   = 8;
constexpr int HGD  = 2048;

// ---------------- fp32 -> fp16 vectorized convert (8 elems/thread) ---------
__global__ __launch_bounds__(256) void conv_f32_f16_kernel(
    const float* __restrict__ in, f16* __restrict__ out)
{
    size_t i = ((size_t)blockIdx.x * 256 + threadIdx.x) * 8;
    const float4* p = (const float4*)(in + i);
    float4 a = p[0], b = p[1];
    f16x8 v = {(f16)a.x, (f16)a.y, (f16)a.z, (f16)a.w,
               (f16)b.x, (f16)b.y, (f16)b.z, (f16)b.w};
    *(f16x8*)(out + i) = v;
}

// transpose+convert: W[z][K][N] f32 -> Wt[z*zstride + n*ldo + z*kostep + k]
__global__ __launch_bounds__(256) void transpose_f32_f16_kernel(
    const float* __restrict__ W, f16* __restrict__ Wt, int K, int N,
    int ldo, size_t zstride, int kostep)
{
    const int z = blockIdx.z;
    W += (size_t)z * K * N;
    f16* base = Wt + (size_t)z * zstride + (size_t)z * kostep;
    __shared__ float t[64][65];
    int n0 = blockIdx.x * 64, k0 = blockIdx.y * 64;
    int tx = threadIdx.x & 63, ty = threadIdx.x >> 6;
#pragma unroll
    for (int i = 0; i < 16; i++) {
        int k = i * 4 + ty;
        t[k][tx] = W[(size_t)(k0 + k) * N + n0 + tx];
    }
    __syncthreads();
#pragma unroll
    for (int i = 0; i < 16; i++) {
        int n = i * 4 + ty;
        base[(size_t)(n0 + n) * ldo + k0 + tx] = (f16)t[tx][n];
    }
}

// ---------------- async global->LDS (16B per lane, wave-uniform dest) ------
DI void gload_lds16(const void* g, void* l)
{
    typedef const __attribute__((address_space(1))) unsigned int as1_t;
    typedef __attribute__((address_space(3))) unsigned int as3_t;
    __builtin_amdgcn_global_load_lds(
        (as1_t*)(unsigned long long)(__SIZE_TYPE__)g,
        (as3_t*)(unsigned int)(__SIZE_TYPE__)l,
        16, 0, 0);
}

// phase sync: head = bare barrier; tail = sched_barrier + barrier + clobber.
#define SYNC_HEAD    __builtin_amdgcn_s_barrier();
#define SYNC_TAIL                                                              \
    __builtin_amdgcn_sched_barrier(0);                                         \
    __builtin_amdgcn_s_barrier();                                              \
    asm volatile("" ::: "memory");

#define VM8 asm volatile("s_waitcnt vmcnt(8)");
#define VM6 asm volatile("s_waitcnt vmcnt(6)");
#define VM4 asm volatile("s_waitcnt vmcnt(4)");
#define VM2 asm volatile("s_waitcnt vmcnt(2)");
#define VM0 asm volatile("s_waitcnt vmcnt(0)");

// ---------------------------------------------------------------------------
// gemm256: BM=256, BN=256, BK=64, 8 waves 2Mx4N. blockIdx.z = sub-expert.
// 2 phases per K-tile, 32 MFMA each.
// ---------------------------------------------------------------------------
template <bool RELU, bool GSCALE>
__global__ __launch_bounds__(512, 2) void gemm256_kernel(
    const f16* __restrict__ A, const f16* __restrict__ Bt,
    const float* __restrict__ bias, const float* __restrict__ gate,
    f16* __restrict__ Cptr, int M, int N, int K, int ldc, int e0)
{
    constexpr int BM = 256, BN = 256, BK = 64;
    constexpr int AT = BM * BK * 2, BT = BN * BK * 2;
    __shared__ __align__(16) f16 sA[2][BM * BK];
    __shared__ __align__(16) f16 sB[2][BN * BK];
    const char* sAc = (const char*)sA;
    const char* sBc = (const char*)sB;

    const int z = blockIdx.z;
    Bt   += (size_t)z * N * K;
    bias += (size_t)z * N;

    const int tid = threadIdx.x, wid = tid >> 6, lane = tid & 63;
    const int wm = wid >> 2, wn = wid & 3;
    const int nwg = gridDim.x, bid = blockIdx.x;
    const int wg = (bid & 7) * (nwg >> 3) + (bid >> 3);
    const int gx = N / BN;
    const size_t bm = (size_t)(wg / gx) * BM;
    const size_t bn = (size_t)(wg % gx) * BN;

    f32x4 acc[8][4] = {};

    const int rho  = tid >> 3;
    const int slot = (((tid & 7) << 4) ^ (((tid >> 3) & 7) << 4));
    const f16* pA = A  + (bm + rho) * (size_t)K + (slot >> 1);
    const f16* pB = Bt + (bn + rho) * (size_t)K + (slot >> 1);

    auto stA = [&](int b, int q, int T) {
        gload_lds16(pA + ((size_t)q * 64) * K + (size_t)T * BK,
                    (char*)sAc + b * AT + q * 8192 + wid * 1024);
    };
    auto stB = [&](int b, int q, int T) {
        gload_lds16(pB + ((size_t)q * 64) * K + (size_t)T * BK,
                    (char*)sBc + b * BT + q * 8192 + wid * 1024);
    };

    int offA0[8], offB0[4];
#pragma unroll
    for (int f = 0; f < 8; f++) {
        int r = wm * 128 + f * 16 + (lane & 15);
        offA0[f] = r * 128 + ((((lane >> 4) << 4)) ^ ((r & 7) << 4));
    }
#pragma unroll
    for (int f = 0; f < 4; f++) {
        int r = wn * 64 + f * 16 + (lane & 15);
        offB0[f] = r * 128 + ((((lane >> 4) << 4)) ^ ((r & 7) << 4));
    }

    f16x8 av[4][2], bv0[2][2], bv1[2][2];

#define LDAQ(B, MH)                                                            \
    _Pragma("unroll") for (int f = 0; f < 4; f++)                              \
    _Pragma("unroll") for (int kc = 0; kc < 2; kc++)                           \
        av[f][kc] = *(const f16x8*)(sAc + (B) * AT + (offA0[(MH)*4+f] ^ (kc << 6)));
#define LDBH(B, NH, BV)                                                        \
    _Pragma("unroll") for (int f = 0; f < 2; f++)                              \
    _Pragma("unroll") for (int kc = 0; kc < 2; kc++)                           \
        BV[f][kc] = *(const f16x8*)(sBc + (B) * BT + (offB0[(NH)*2+f] ^ (kc << 6)));
#define MFMA_MH(MH)                                                            \
    __builtin_amdgcn_s_setprio(1);                                             \
    _Pragma("unroll") for (int f = 0; f < 4; f++)                              \
    _Pragma("unroll") for (int g = 0; g < 2; g++)                              \
    _Pragma("unroll") for (int kc = 0; kc < 2; kc++) {                         \
        acc[(MH)*4+f][g]   = __builtin_amdgcn_mfma_f32_16x16x32_f16(           \
            av[f][kc], bv0[g][kc], acc[(MH)*4+f][g],   0, 0, 0);               \
        acc[(MH)*4+f][2+g] = __builtin_amdgcn_mfma_f32_16x16x32_f16(           \
            av[f][kc], bv1[g][kc], acc[(MH)*4+f][2+g], 0, 0, 0);               \
    }                                                                          \
    __builtin_amdgcn_s_setprio(0);

#define TILE_A(B, STAGE, VM)                                                   \
  { LDAQ(B, 0) LDBH(B, 0, bv0) LDBH(B, 1, bv1)                                 \
    STAGE                                                                      \
    SYNC_HEAD MFMA_MH(0) VM SYNC_TAIL }
#define TILE_B(B, STAGE, VM)                                                   \
  { LDAQ(B, 1)                                                                 \
    STAGE                                                                      \
    SYNC_HEAD MFMA_MH(1) VM SYNC_TAIL }

    const int NT = K / BK;

    // prologue: tile0 full (8: q0,q2,B,q1,q3), tile1 {q0,q2,B} (6);
    // vmcnt(6) drains the 8 tile-0 loads.
    stA(0,0,0); stA(0,2,0); stB(0,0,0); stB(0,1,0); stB(0,2,0); stB(0,3,0);
    stA(0,1,0); stA(0,3,0);
    stA(1,0,1); stA(1,2,1); stB(1,0,1); stB(1,1,1); stB(1,2,1); stB(1,3,1);
    VM6
    __builtin_amdgcn_s_barrier();
    asm volatile("" ::: "memory");

    for (int t = 0; t < NT - 2; t += 2) {
        TILE_A(0, { stA(1,1,t+1); stA(1,3,t+1); }, VM8)
        TILE_B(0, { stA(0,0,t+2); stA(0,2,t+2);
                    stB(0,0,t+2); stB(0,1,t+2); stB(0,2,t+2); stB(0,3,t+2); }, VM8)
        TILE_A(1, { stA(0,1,t+2); stA(0,3,t+2); }, VM8)
        TILE_B(1, { stA(1,0,t+3); stA(1,2,t+3);
                    stB(1,0,t+3); stB(1,1,t+3); stB(1,2,t+3); stB(1,3,t+3); }, VM8)
    }
    // peel tiles NT-2 (buf0), NT-1 (buf1)
    TILE_A(0, { stA(1,1,NT-1); stA(1,3,NT-1); }, VM8)
    TILE_B(0, {}, VM2)
    TILE_A(1, {}, VM0)
    TILE_B(1, {}, )

#undef LDAQ
#undef LDBH
#undef MFMA_MH
#undef TILE_A
#undef TILE_B

    const size_t row0 = bm + (size_t)wm * 128;
    const int col0 = (int)bn + wn * 64;
    const int c0 = lane & 15, r0 = (lane >> 4) * 4;
    f16* Cz = Cptr + (size_t)z * N;
#pragma unroll
    for (int fm = 0; fm < 8; fm++)
#pragma unroll
        for (int r = 0; r < 4; r++) {
            const size_t row = row0 + fm * 16 + r0 + r;
            float g = 1.0f;
            if constexpr (GSCALE) g = gate[row * NE + e0 + z];
#pragma unroll
            for (int n = 0; n < 4; n++) {
                const size_t col = (size_t)col0 + n * 16 + c0;
                float v = acc[fm][n][r] + bias[col];
                if constexpr (RELU) v = fmaxf(v, 0.0f);
                if constexpr (GSCALE) v *= g;
                Cz[row * (size_t)ldc + col] = (f16)v;
            }
        }
}

// ---------------------------------------------------------------------------
// gemmO: BM=256, BN=128, BK=64, 8 waves 2Mx4N. B row stride = ldb.
// 2 phases per K-tile, 16 MFMA each.
// ---------------------------------------------------------------------------
template <bool ACCUM, int GN>
__global__ __launch_bounds__(512, 2) void gemmO_kernel(
    const f16* __restrict__ A, const f16* __restrict__ Bt,
    const float* __restrict__ bias, const float* __restrict__ gate,
    float* __restrict__ Cptr, int M, int N, int K, int ldb, int e0)
{
    constexpr int BM = 256, BN = 128, BK = 64;
    constexpr int AT = BM * BK * 2, BT = BN * BK * 2;
    __shared__ __align__(16) f16 sA[2][BM * BK];
    __shared__ __align__(16) f16 sB[2][BN * BK];
    const char* sAc = (const char*)sA;
    const char* sBc = (const char*)sB;

    const int tid = threadIdx.x, wid = tid >> 6, lane = tid & 63;
    const int wm = wid >> 2, wn = wid & 3;
    const int nwg = gridDim.x, bid = blockIdx.x;
    const int wg = (bid & 7) * (nwg >> 3) + (bid >> 3);
    const int gx = N / BN;
    const size_t bm = (size_t)(wg / gx) * BM;
    const size_t bn = (size_t)(wg % gx) * BN;

    f32x4 acc[8][2] = {};

    const int rho  = tid >> 3;
    const int slot = (((tid & 7) << 4) ^ (((tid >> 3) & 7) << 4));
    const f16* pA = A  + (bm + rho) * (size_t)K   + (slot >> 1);
    const f16* pB = Bt + (bn + rho) * (size_t)ldb + (slot >> 1);

    auto stA = [&](int b, int q, int T) {
        gload_lds16(pA + ((size_t)q * 64) * K + (size_t)T * BK,
                    (char*)sAc + b * AT + q * 8192 + wid * 1024);
    };
    auto stB = [&](int b, int q, int T) {
        gload_lds16(pB + ((size_t)q * 64) * ldb + (size_t)T * BK,
                    (char*)sBc + b * BT + q * 8192 + wid * 1024);
    };

    int offA0[8], offB0[2];
#pragma unroll
    for (int f = 0; f < 8; f++) {
        int r = wm * 128 + f * 16 + (lane & 15);
        offA0[f] = r * 128 + ((((lane >> 4) << 4)) ^ ((r & 7) << 4));
    }
#pragma unroll
    for (int f = 0; f < 2; f++) {
        int r = wn * 32 + f * 16 + (lane & 15);
        offB0[f] = r * 128 + ((((lane >> 4) << 4)) ^ ((r & 7) << 4));
    }

    f16x8 av[4][2], bv[2][2];

#define LDAO(B, MH)                                                            \
    _Pragma("unroll") for (int f = 0; f < 4; f++)                              \
    _Pragma("unroll") for (int kc = 0; kc < 2; kc++)                           \
        av[f][kc] = *(const f16x8*)(sAc + (B) * AT + (offA0[(MH)*4+f] ^ (kc << 6)));
#define LDBA(B)                                                                \
    _Pragma("unroll") for (int f = 0; f < 2; f++)                              \
    _Pragma("unroll") for (int kc = 0; kc < 2; kc++)                           \
        bv[f][kc] = *(const f16x8*)(sBc + (B) * BT + (offB0[f] ^ (kc << 6)));
#define MFMAO(MH)                                                              \
    __builtin_amdgcn_s_setprio(1);                                             \
    _Pragma("unroll") for (int f = 0; f < 4; f++)                              \
    _Pragma("unroll") for (int g = 0; g < 2; g++)                              \
    _Pragma("unroll") for (int kc = 0; kc < 2; kc++)                           \
        acc[(MH)*4+f][g] = __builtin_amdgcn_mfma_f32_16x16x32_f16(             \
            av[f][kc], bv[g][kc], acc[(MH)*4+f][g], 0, 0, 0);                  \
    __builtin_amdgcn_s_setprio(0);

#define TO_A(B, STAGE, VM)                                                     \
  { LDAO(B, 0) LDBA(B)                                                         \
    STAGE                                                                      \
    SYNC_HEAD MFMAO(0) VM SYNC_TAIL }
#define TO_B(B, STAGE, VM)                                                     \
  { LDAO(B, 1)                                                                 \
    STAGE                                                                      \
    SYNC_HEAD MFMAO(1) VM SYNC_TAIL }

    const int NT = K / BK;

    // prologue: tile0 full (6: q0,q2,B,q1,q3), tile1 {q0,q2,B} (4);
    // vmcnt(4) drains the 6 tile-0 loads.
    stA(0,0,0); stA(0,2,0); stB(0,0,0); stB(0,1,0);
    stA(0,1,0); stA(0,3,0);
    stA(1,0,1); stA(1,2,1); stB(1,0,1); stB(1,1,1);
    VM4
    __builtin_amdgcn_s_barrier();
    asm volatile("" ::: "memory");

    for (int t = 0; t < NT - 2; t += 2) {
        TO_A(0, { stA(1,1,t+1); stA(1,3,t+1); }, VM6)
        TO_B(0, { stA(0,0,t+2); stA(0,2,t+2); stB(0,0,t+2); stB(0,1,t+2); }, VM6)
        TO_A(1, { stA(0,1,t+2); stA(0,3,t+2); }, VM6)
        TO_B(1, { stA(1,0,t+3); stA(1,2,t+3); stB(1,0,t+3); stB(1,1,t+3); }, VM6)
    }
    // peel tiles NT-2 (buf0), NT-1 (buf1)
    TO_A(0, { stA(1,1,NT-1); stA(1,3,NT-1); }, VM6)
    TO_B(0, {}, VM2)
    TO_A(1, {}, VM0)
    TO_B(1, {}, )

#undef LDAO
#undef LDBA
#undef MFMAO
#undef TO_A
#undef TO_B

    const size_t row0 = bm + (size_t)wm * 128;
    const int col0 = (int)bn + wn * 32;
    const int c0 = lane & 15, r0 = (lane >> 4) * 4;
#pragma unroll
    for (int fm = 0; fm < 8; fm++)
#pragma unroll
        for (int r = 0; r < 4; r++) {
            const size_t row = row0 + fm * 16 + r0 + r;
            if constexpr (GN == 0) {
                const float g = gate[row * NE];
#pragma unroll
                for (int n = 0; n < 2; n++) {
                    const size_t col = (size_t)col0 + n * 16 + c0;
                    float v = (acc[fm][n][r] + bias[col]) * g;
                    float* p = Cptr + row * (size_t)N + col;
                    *p = ACCUM ? (*p + v) : v;
                }
            } else {
                float gv[GN];
#pragma unroll
                for (int j = 0; j < GN; j++) gv[j] = gate[row * NE + e0 + j];
#pragma unroll
                for (int n = 0; n < 2; n++) {
                    const size_t col = (size_t)col0 + n * 16 + c0;
                    float bb = 0.f;
#pragma unroll
                    for (int j = 0; j < GN; j++)
                        bb = fmaf(gv[j], bias[(size_t)(e0 + j) * N + col], bb);
                    float v = acc[fm][n][r] + bb;
                    float* p = Cptr + row * (size_t)N + col;
                    *p = ACCUM ? (*p + v) : v;
                }
            }
        }
}

// --------- gating head: logits = gh@gw2 + gb2, softmax -> gates fp32 -------
__global__ __launch_bounds__(256) void gate_softmax_kernel(
    const f16* __restrict__ gh, const float* __restrict__ gw2,
    const float* __restrict__ gb2, float* __restrict__ gates)
{
    const int row  = blockIdx.x * 4 + (threadIdx.x >> 6);
    const int lane = threadIdx.x & 63;
    const f16* r = gh + (size_t)row * HGD;
    float acc[NE] = {};
    for (int kb = lane * 8; kb < HGD; kb += 512) {
        f16x8 v = *(const f16x8*)(r + kb);
#pragma unroll
        for (int j = 0; j < 8; j++) {
            float h = (float)v[j];
            const float* w = gw2 + (size_t)(kb + j) * NE;
#pragma unroll
            for (int e = 0; e < NE; e++) acc[e] = fmaf(h, w[e], acc[e]);
        }
    }
#pragma unroll
    for (int off = 32; off > 0; off >>= 1)
#pragma unroll
        for (int e = 0; e < NE; e++) acc[e] += __shfl_down(acc[e], off, 64);
    if (lane == 0) {
        float l[NE], m = -1e30f;
#pragma unroll
        for (int e = 0; e < NE; e++) { l[e] = acc[e] + gb2[e]; m = fmaxf(m, l[e]); }
        float s = 0.f;
#pragma unroll
        for (int e = 0; e < NE; e++) { l[e] = expf(l[e] - m); s += l[e]; }
        float inv = 1.0f / s;
#pragma unroll
        for (int e = 0; e < NE; e++) gates[(size_t)row * NE + e] = l[e] * inv;
    }
}

// ---------------------------------------------------------------------------
extern "C" void kernel_launch(void* const* d_in, const int* in_sizes, int n_in,
                              void* d_out, int out_size, void* d_ws, size_t ws_size,
                              hipStream_t stream)
{
    const float* x   = (const float*)d_in[0];
    const float* gw1 = (const float*)d_in[1];
    const float* gb1 = (const float*)d_in[2];
    const float* gw2 = (const float*)d_in[3];
    const float* gb2 = (const float*)d_in[4];
    const float* ew1 = (const float*)d_in[5];
    const float* eb1 = (const float*)d_in[6];
    const float* ew2 = (const float*)d_in[7];
    const float* eb2 = (const float*)d_in[8];
    float* out = (float*)d_out;

    const size_t SZ_GATES = 256 << 10;
    const size_t SZ_X16   = (size_t)BSZ * IND * 2;
    const size_t SZ_WBUF  = (size_t)HID * IND * 2;
    const size_t SZ_W1ALL = (size_t)NE * HID * IND * 2;
    const size_t SZ_W2ALL = (size_t)NE * OUTD * HID * 2;
    const size_t SZ_HB1   = (size_t)BSZ * HID * 2;
    const size_t BASE     = SZ_GATES + SZ_X16 + SZ_W1ALL + SZ_W2ALL;
    const size_t NEED_G4  = BASE + 4 * SZ_HB1;
    const size_t NEED_G2  = BASE + 2 * SZ_HB1;
    const size_t NEED_G1  = BASE + 1 * SZ_HB1;

    char* p = (char*)d_ws;
    float* gates = (float*)p;  p += SZ_GATES;
    f16* x16 = (f16*)p;        p += SZ_X16;

    conv_f32_f16_kernel<<<(BSZ * IND) / (256 * 8), 256, 0, stream>>>(x, x16);

    if (ws_size >= NEED_G2) {
        const int G = (ws_size >= NEED_G4) ? 4 : 2;
        f16* w1all = (f16*)p;  p += SZ_W1ALL;
        f16* w2cat = (f16*)p;  p += SZ_W2ALL;
        f16* hbufG = (f16*)p;
        f16* gh    = hbufG;

        transpose_f32_f16_kernel<<<dim3(HGD / 64, IND / 64, 1), 256, 0, stream>>>(
            gw1, w1all, IND, HGD, IND, 0, 0);
        gemm256_kernel<true, false>
            <<<dim3((HGD / 256) * (BSZ / 256), 1, 1), 512, 0, stream>>>(
                x16, w1all, gb1, nullptr, gh, BSZ, HGD, IND, HGD, 0);
        gate_softmax_kernel<<<BSZ / 4, 256, 0, stream>>>(gh, gw2, gb2, gates);

        transpose_f32_f16_kernel<<<dim3(HID / 64, IND / 64, NE), 256, 0, stream>>>(
            ew1, w1all, IND, HID, IND, (size_t)HID * IND, 0);
        transpose_f32_f16_kernel<<<dim3(OUTD / 64, HID / 64, NE), 256, 0, stream>>>(
            ew2, w2cat, HID, OUTD, NE * HID, 0, HID);

        for (int g = 0; g < NE / G; g++) {
            gemm256_kernel<true, true>
                <<<dim3((HID / 256) * (BSZ / 256), 1, G), 512, 0, stream>>>(
                    x16, w1all + (size_t)g * G * HID * IND, eb1 + g * G * HID,
                    gates, hbufG, BSZ, HID, IND, G * HID, g * G);
            if (G == 4) {
                if (g == 0)
                    gemmO_kernel<false, 4>
                        <<<(OUTD / 128) * (BSZ / 256), 512, 0, stream>>>(
                            hbufG, w2cat + (size_t)g * G * HID, eb2, gates, out,
                            BSZ, OUTD, G * HID, NE * HID, g * G);
                else
                    gemmO_kernel<true, 4>
                        <<<(OUTD / 128) * (BSZ / 256), 512, 0, stream>>>(
                            hbufG, w2cat + (size_t)g * G * HID, eb2, gates, out,
                            BSZ, OUTD, G * HID, NE * HID, g * G);
            } else {
                if (g == 0)
                    gemmO_kernel<false, 2>
                        <<<(OUTD / 128) * (BSZ / 256), 512, 0, stream>>>(
                            hbufG, w2cat + (size_t)g * G * HID, eb2, gates, out,
                            BSZ, OUTD, G * HID, NE * HID, g * G);
                else
                    gemmO_kernel<true, 2>
                        <<<(OUTD / 128) * (BSZ / 256), 512, 0, stream>>>(
                            hbufG, w2cat + (size_t)g * G * HID, eb2, gates, out,
                            BSZ, OUTD, G * HID, NE * HID, g * G);
            }
        }
    } else if (ws_size >= NEED_G1) {
        f16* w1all = (f16*)p;  p += SZ_W1ALL;
        f16* w2all = (f16*)p;  p += SZ_W2ALL;
        f16* hbuf  = (f16*)p;
        f16* gh    = hbuf;

        transpose_f32_f16_kernel<<<dim3(HGD / 64, IND / 64, 1), 256, 0, stream>>>(
            gw1, w1all, IND, HGD, IND, 0, 0);
        gemm256_kernel<true, false>
            <<<dim3((HGD / 256) * (BSZ / 256), 1, 1), 512, 0, stream>>>(
                x16, w1all, gb1, nullptr, gh, BSZ, HGD, IND, HGD, 0);
        gate_softmax_kernel<<<BSZ / 4, 256, 0, stream>>>(gh, gw2, gb2, gates);

        transpose_f32_f16_kernel<<<dim3(HID / 64, IND / 64, NE), 256, 0, stream>>>(
            ew1, w1all, IND, HID, IND, (size_t)HID * IND, 0);
        transpose_f32_f16_kernel<<<dim3(OUTD / 64, HID / 64, NE), 256, 0, stream>>>(
            ew2, w2all, HID, OUTD, HID, (size_t)OUTD * HID, 0);

        for (int e = 0; e < NE; e++) {
            gemm256_kernel<true, false>
                <<<dim3((HID / 256) * (BSZ / 256), 1, 1), 512, 0, stream>>>(
                    x16, w1all + (size_t)e * HID * IND, eb1 + (size_t)e * HID,
                    nullptr, hbuf, BSZ, HID, IND, HID, 0);
            if (e == 0)
                gemmO_kernel<false, 0><<<(OUTD / 128) * (BSZ / 256), 512, 0, stream>>>(
                    hbuf, w2all + (size_t)e * OUTD * HID, eb2 + (size_t)e * OUTD,
                    gates + e, out, BSZ, OUTD, HID, HID, 0);
            else
                gemmO_kernel<true, 0><<<(OUTD / 128) * (BSZ / 256), 512, 0, stream>>>(
                    hbuf, w2all + (size_t)e * OUTD * HID, eb2 + (size_t)e * OUTD,
                    gates + e, out, BSZ, OUTD, HID, HID, 0);
        }
    } else {
        f16* wbuf = (f16*)p;   p += SZ_WBUF;
        f16* hbuf = (f16*)p;
        f16* gh   = hbuf;

        transpose_f32_f16_kernel<<<dim3(HGD / 64, IND / 64, 1), 256, 0, stream>>>(
            gw1, wbuf, IND, HGD, IND, 0, 0);
        gemm256_kernel<true, false>
            <<<dim3((HGD / 256) * (BSZ / 256), 1, 1), 512, 0, stream>>>(
                x16, wbuf, gb1, nullptr, gh, BSZ, HGD, IND, HGD, 0);
        gate_softmax_kernel<<<BSZ / 4, 256, 0, stream>>>(gh, gw2, gb2, gates);

        for (int e = 0; e < NE; e++) {
            transpose_f32_f16_kernel<<<dim3(HID / 64, IND / 64, 1), 256, 0, stream>>>(
                ew1 + (size_t)e * IND * HID, wbuf, IND, HID, IND, 0, 0);
            gemm256_kernel<true, false>
                <<<dim3((HID / 256) * (BSZ / 256), 1, 1), 512, 0, stream>>>(
                    x16, wbuf, eb1 + (size_t)e * HID, nullptr, hbuf,
                    BSZ, HID, IND, HID, 0);

            transpose_f32_f16_kernel<<<dim3(OUTD / 64, HID / 64, 1), 256, 0, stream>>>(
                ew2 + (size_t)e * HID * OUTD, wbuf, HID, OUTD, HID, 0, 0);
            if (e == 0)
                gemmO_kernel<false, 0><<<(OUTD / 128) * (BSZ / 256), 512, 0, stream>>>(
                    hbuf, wbuf, eb2 + (size_t)e * OUTD, gates + e, out,
                    BSZ, OUTD, HID, HID, 0);
            else
                gemmO_kernel<true, 0><<<(OUTD / 128) * (BSZ / 256), 512, 0, stream>>>(
                    hbuf, wbuf, eb2 + (size_t)e * OUTD, gates + e, out,
                    BSZ, OUTD, HID, HID, 0);
        }
    }
}

// Round 16
// 1310.989 us; speedup vs baseline: 1.0208x; 1.0208x over previous
//
#include <hip/hip_runtime.h>

// ---------------------------------------------------------------------------
// MoE forward: gating MLP + 8 dense experts + gate-weighted combine.
// r16 = r13 (best verified: grouped G=4 fusion, gate folded into hs, bias-dot
// OUT epilogue, cross-barrier read/MFMA overlap, counted vmcnt, T1/T2/T5) +
// vectorized transpose writes (f16x4, 8B/lane; conflict-free LDS reads).
// 12 schedule variants all pin at 40-43% MfmaUtil -> r13 schedule is the
// plain-HIP ceiling for these shapes; this round trims non-GEMM overhead.
// ---------------------------------------------------------------------------

#define DI __device__ __forceinline__

typedef _Float16 f16;
typedef _Float16 f16x4 __attribute__((ext_vector_type(4)));
typedef _Float16 f16x8 __attribute__((ext_vector_type(8)));
typedef float f32x4 __attribute__((ext_vector_type(4)));

constexpr int BSZ  = 8192;
constexpr int IND  = 1024;
constexpr int HID  = 4096;
constexpr int OUTD = 1024;
constexpr int NE   = 8;
constexpr int HGD  = 2048;

// ---------------- fp32 -> fp16 vectorized convert (8 elems/thread) ---------
__global__ __launch_bounds__(256) void conv_f32_f16_kernel(
    const float* __restrict__ in, f16* __restrict__ out)
{
    size_t i = ((size_t)blockIdx.x * 256 + threadIdx.x) * 8;
    const float4* p = (const float4*)(in + i);
    float4 a = p[0], b = p[1];
    f16x8 v = {(f16)a.x, (f16)a.y, (f16)a.z, (f16)a.w,
               (f16)b.x, (f16)b.y, (f16)b.z, (f16)b.w};
    *(f16x8*)(out + i) = v;
}

// transpose+convert: W[z][K][N] f32 -> Wt[z*zstride + n*ldo + z*kostep + k]
// Write side vectorized: each thread stores f16x4 (8B); LDS reads 2-way max.
__global__ __launch_bounds__(256) void transpose_f32_f16_kernel(
    const float* __restrict__ W, f16* __restrict__ Wt, int K, int N,
    int ldo, size_t zstride, int kostep)
{
    const int z = blockIdx.z;
    W += (size_t)z * K * N;
    f16* base = Wt + (size_t)z * zstride + (size_t)z * kostep;
    __shared__ float t[64][65];
    int n0 = blockIdx.x * 64, k0 = blockIdx.y * 64;
    int tx = threadIdx.x & 63, ty = threadIdx.x >> 6;
#pragma unroll
    for (int i = 0; i < 16; i++) {
        int k = i * 4 + ty;
        t[k][tx] = W[(size_t)(k0 + k) * N + n0 + tx];   // t[k][n] = W[k][n]
    }
    __syncthreads();
    const int kq = threadIdx.x & 15, ny = threadIdx.x >> 4;   // kq:k-quad, ny:n
#pragma unroll
    for (int i = 0; i < 4; i++) {
        int n = i * 16 + ny;
        f16x4 v = {(f16)t[kq * 4 + 0][n], (f16)t[kq * 4 + 1][n],
                   (f16)t[kq * 4 + 2][n], (f16)t[kq * 4 + 3][n]};
        *(f16x4*)(&base[(size_t)(n0 + n) * ldo + k0 + kq * 4]) = v;
    }
}

// ---------------- async global->LDS (16B per lane, wave-uniform dest) ------
DI void gload_lds16(const void* g, void* l)
{
    typedef const __attribute__((address_space(1))) unsigned int as1_t;
    typedef __attribute__((address_space(3))) unsigned int as3_t;
    __builtin_amdgcn_global_load_lds(
        (as1_t*)(unsigned long long)(__SIZE_TYPE__)g,
        (as3_t*)(unsigned int)(__SIZE_TYPE__)l,
        16, 0, 0);
}

// phase sync: head = bare barrier; tail = sched_barrier + barrier + clobber.
#define SYNC_HEAD    __builtin_amdgcn_s_barrier();
#define SYNC_TAIL                                                              \
    __builtin_amdgcn_sched_barrier(0);                                         \
    __builtin_amdgcn_s_barrier();                                              \
    asm volatile("" ::: "memory");

// ---------------------------------------------------------------------------
// gemm256 (r13-verified): BM=256, BN=256, BK=64, 8 waves 2Mx4N.
// blockIdx.z = sub-expert. Cross-barrier read/MFMA overlap.
// ---------------------------------------------------------------------------
template <bool RELU, bool GSCALE>
__global__ __launch_bounds__(512, 2) void gemm256_kernel(
    const f16* __restrict__ A, const f16* __restrict__ Bt,
    const float* __restrict__ bias, const float* __restrict__ gate,
    f16* __restrict__ Cptr, int M, int N, int K, int ldc, int e0)
{
    constexpr int BM = 256, BN = 256, BK = 64;
    constexpr int AT = BM * BK * 2, BT = BN * BK * 2;
    __shared__ __align__(16) f16 sA[2][BM * BK];
    __shared__ __align__(16) f16 sB[2][BN * BK];
    const char* sAc = (const char*)sA;
    const char* sBc = (const char*)sB;

    const int z = blockIdx.z;
    Bt   += (size_t)z * N * K;
    bias += (size_t)z * N;

    const int tid = threadIdx.x, wid = tid >> 6, lane = tid & 63;
    const int wm = wid >> 2, wn = wid & 3;
    const int nwg = gridDim.x, bid = blockIdx.x;
    const int wg = (bid & 7) * (nwg >> 3) + (bid >> 3);
    const int gx = N / BN;
    const size_t bm = (size_t)(wg / gx) * BM;
    const size_t bn = (size_t)(wg % gx) * BN;

    f32x4 acc[8][4] = {};

    const int rho  = tid >> 3;
    const int slot = (((tid & 7) << 4) ^ (((tid >> 3) & 7) << 4));
    const f16* pA = A  + (bm + rho) * (size_t)K + (slot >> 1);
    const f16* pB = Bt + (bn + rho) * (size_t)K + (slot >> 1);

    auto stA = [&](int b, int q, int T) {
        gload_lds16(pA + ((size_t)q * 64) * K + (size_t)T * BK,
                    (char*)sAc + b * AT + q * 8192 + wid * 1024);
    };
    auto stB = [&](int b, int q, int T) {
        gload_lds16(pB + ((size_t)q * 64) * K + (size_t)T * BK,
                    (char*)sBc + b * BT + q * 8192 + wid * 1024);
    };

    int offA0[8], offB0[4];
#pragma unroll
    for (int f = 0; f < 8; f++) {
        int r = wm * 128 + f * 16 + (lane & 15);
        offA0[f] = r * 128 + ((((lane >> 4) << 4)) ^ ((r & 7) << 4));
    }
#pragma unroll
    for (int f = 0; f < 4; f++) {
        int r = wn * 64 + f * 16 + (lane & 15);
        offB0[f] = r * 128 + ((((lane >> 4) << 4)) ^ ((r & 7) << 4));
    }

    f16x8 av[4][2], bv0[2][2], bv1[2][2];

#define LDAQ(B, MH)                                                            \
    _Pragma("unroll") for (int f = 0; f < 4; f++)                              \
    _Pragma("unroll") for (int kc = 0; kc < 2; kc++)                           \
        av[f][kc] = *(const f16x8*)(sAc + (B) * AT + (offA0[(MH)*4+f] ^ (kc << 6)));
#define LDBH(B, NH, BV)                                                        \
    _Pragma("unroll") for (int f = 0; f < 2; f++)                              \
    _Pragma("unroll") for (int kc = 0; kc < 2; kc++)                           \
        BV[f][kc] = *(const f16x8*)(sBc + (B) * BT + (offB0[(NH)*2+f] ^ (kc << 6)));
#define QUAD(MH, NH, BV)                                                       \
    __builtin_amdgcn_s_setprio(1);                                             \
    _Pragma("unroll") for (int f = 0; f < 4; f++)                              \
    _Pragma("unroll") for (int g = 0; g < 2; g++)                              \
    _Pragma("unroll") for (int kc = 0; kc < 2; kc++)                           \
        acc[(MH)*4+f][(NH)*2+g] = __builtin_amdgcn_mfma_f32_16x16x32_f16(      \
            av[f][kc], BV[g][kc], acc[(MH)*4+f][(NH)*2+g], 0, 0, 0);           \
    __builtin_amdgcn_s_setprio(0);

    const int NT = K / BK, NI = NT / 2;

    stA(0,0,0); stA(0,2,0); stB(0,0,0); stB(0,1,0); stB(0,2,0); stB(0,3,0);
    stA(0,1,0); stA(0,3,0);
    stA(1,0,1); stA(1,2,1); stB(1,0,1); stB(1,1,1); stB(1,2,1); stB(1,3,1);
    asm volatile("s_waitcnt vmcnt(6)");
    __builtin_amdgcn_s_barrier();
    asm volatile("" ::: "memory");

    for (int i = 0; i < NI - 1; ++i) {
        const int t = 2 * i;
        // ---- buf0 (tile t) ----
        LDAQ(0, 0) LDBH(0, 0, bv0) LDBH(0, 1, bv1)        // P1 pre-reads
        stA(1, 1, t + 1); stA(1, 3, t + 1);
        SYNC_HEAD
        QUAD(0, 0, bv0)
        SYNC_TAIL
        stA(0, 0, t + 2); stA(0, 2, t + 2);               // P2
        SYNC_HEAD
        QUAD(0, 1, bv1)
        LDAQ(0, 1)                                        // post-read mh1
        SYNC_TAIL
        stB(0, 0, t + 2); stB(0, 1, t + 2);               // P3
        SYNC_HEAD
        QUAD(1, 1, bv1)
        SYNC_TAIL
        stB(0, 2, t + 2); stB(0, 3, t + 2);               // P4
        SYNC_HEAD
        QUAD(1, 0, bv0)
        asm volatile("s_waitcnt vmcnt(6)");
        SYNC_TAIL
        // ---- buf1 (tile t+1) ----
        LDAQ(1, 0) LDBH(1, 0, bv0) LDBH(1, 1, bv1)        // P5 pre-reads
        stA(0, 1, t + 2); stA(0, 3, t + 2);
        SYNC_HEAD
        QUAD(0, 0, bv0)
        SYNC_TAIL
        stA(1, 0, t + 3); stA(1, 2, t + 3);               // P6
        SYNC_HEAD
        QUAD(0, 1, bv1)
        LDAQ(1, 1)                                        // post-read mh1
        SYNC_TAIL
        stB(1, 0, t + 3); stB(1, 1, t + 3);               // P7
        SYNC_HEAD
        QUAD(1, 1, bv1)
        SYNC_TAIL
        stB(1, 2, t + 3); stB(1, 3, t + 3);               // P8
        SYNC_HEAD
        QUAD(1, 0, bv0)
        asm volatile("s_waitcnt vmcnt(6)");
        SYNC_TAIL
    }
    {   // final iteration (tiles NT-2, NT-1)
        LDAQ(0, 0) LDBH(0, 0, bv0) LDBH(0, 1, bv1)
        stA(1, 1, NT - 1); stA(1, 3, NT - 1);
        SYNC_HEAD
        QUAD(0, 0, bv0)
        SYNC_TAIL
        SYNC_HEAD
        QUAD(0, 1, bv1)
        LDAQ(0, 1)
        SYNC_TAIL
        SYNC_HEAD
        QUAD(1, 1, bv1)
        SYNC_TAIL
        SYNC_HEAD
        QUAD(1, 0, bv0)
        asm volatile("s_waitcnt vmcnt(0)");
        SYNC_TAIL
        LDAQ(1, 0) LDBH(1, 0, bv0) LDBH(1, 1, bv1)
        SYNC_HEAD
        QUAD(0, 0, bv0)
        SYNC_TAIL
        SYNC_HEAD
        QUAD(0, 1, bv1)
        LDAQ(1, 1)
        SYNC_TAIL
        SYNC_HEAD
        QUAD(1, 1, bv1)
        SYNC_TAIL
        SYNC_HEAD
        QUAD(1, 0, bv0)
        SYNC_TAIL
    }
#undef LDAQ
#undef LDBH
#undef QUAD

    const size_t row0 = bm + (size_t)wm * 128;
    const int col0 = (int)bn + wn * 64;
    const int c0 = lane & 15, r0 = (lane >> 4) * 4;
    f16* Cz = Cptr + (size_t)z * N;
#pragma unroll
    for (int fm = 0; fm < 8; fm++)
#pragma unroll
        for (int r = 0; r < 4; r++) {
            const size_t row = row0 + fm * 16 + r0 + r;
            float g = 1.0f;
            if constexpr (GSCALE) g = gate[row * NE + e0 + z];
#pragma unroll
            for (int n = 0; n < 4; n++) {
                const size_t col = (size_t)col0 + n * 16 + c0;
                float v = acc[fm][n][r] + bias[col];
                if constexpr (RELU) v = fmaxf(v, 0.0f);
                if constexpr (GSCALE) v *= g;
                Cz[row * (size_t)ldc + col] = (f16)v;
            }
        }
}

// ---------------------------------------------------------------------------
// gemmO (r13-verified): BM=256, BN=128, BK=64, 8 waves 2Mx4N. B stride ldb.
// ---------------------------------------------------------------------------
template <bool ACCUM, int GN>
__global__ __launch_bounds__(512, 2) void gemmO_kernel(
    const f16* __restrict__ A, const f16* __restrict__ Bt,
    const float* __restrict__ bias, const float* __restrict__ gate,
    float* __restrict__ Cptr, int M, int N, int K, int ldb, int e0)
{
    constexpr int BM = 256, BN = 128, BK = 64;
    constexpr int AT = BM * BK * 2, BT = BN * BK * 2;
    __shared__ __align__(16) f16 sA[2][BM * BK];
    __shared__ __align__(16) f16 sB[2][BN * BK];
    const char* sAc = (const char*)sA;
    const char* sBc = (const char*)sB;

    const int tid = threadIdx.x, wid = tid >> 6, lane = tid & 63;
    const int wm = wid >> 2, wn = wid & 3;
    const int nwg = gridDim.x, bid = blockIdx.x;
    const int wg = (bid & 7) * (nwg >> 3) + (bid >> 3);
    const int gx = N / BN;
    const size_t bm = (size_t)(wg / gx) * BM;
    const size_t bn = (size_t)(wg % gx) * BN;

    f32x4 acc[8][2] = {};

    const int rho  = tid >> 3;
    const int slot = (((tid & 7) << 4) ^ (((tid >> 3) & 7) << 4));
    const f16* pA = A  + (bm + rho) * (size_t)K   + (slot >> 1);
    const f16* pB = Bt + (bn + rho) * (size_t)ldb + (slot >> 1);

    auto stA = [&](int b, int q, int T) {
        gload_lds16(pA + ((size_t)q * 64) * K + (size_t)T * BK,
                    (char*)sAc + b * AT + q * 8192 + wid * 1024);
    };
    auto stB = [&](int b, int q, int T) {
        gload_lds16(pB + ((size_t)q * 64) * ldb + (size_t)T * BK,
                    (char*)sBc + b * BT + q * 8192 + wid * 1024);
    };

    int offA0[8], offB0[2];
#pragma unroll
    for (int f = 0; f < 8; f++) {
        int r = wm * 128 + f * 16 + (lane & 15);
        offA0[f] = r * 128 + ((((lane >> 4) << 4)) ^ ((r & 7) << 4));
    }
#pragma unroll
    for (int f = 0; f < 2; f++) {
        int r = wn * 32 + f * 16 + (lane & 15);
        offB0[f] = r * 128 + ((((lane >> 4) << 4)) ^ ((r & 7) << 4));
    }

    f16x8 av[4], bv[2][2];

#define LDA4(B, MH, KC)                                                        \
    _Pragma("unroll") for (int f = 0; f < 4; f++)                              \
        av[f] = *(const f16x8*)(sAc + (B) * AT + (offA0[(MH)*4+f] ^ ((KC) << 6)));
#define LDBA(B)                                                                \
    _Pragma("unroll") for (int f = 0; f < 2; f++)                              \
    _Pragma("unroll") for (int kc = 0; kc < 2; kc++)                           \
        bv[f][kc] = *(const f16x8*)(sBc + (B) * BT + (offB0[f] ^ (kc << 6)));
#define OCT(MH, KC)                                                            \
    __builtin_amdgcn_s_setprio(1);                                             \
    _Pragma("unroll") for (int f = 0; f < 4; f++)                              \
    _Pragma("unroll") for (int g = 0; g < 2; g++)                              \
        acc[(MH)*4+f][g] = __builtin_amdgcn_mfma_f32_16x16x32_f16(             \
            av[f], bv[g][KC], acc[(MH)*4+f][g], 0, 0, 0);                      \
    __builtin_amdgcn_s_setprio(0);

    const int NT = K / BK, NI = NT / 2;

    stA(0,0,0); stA(0,2,0); stB(0,0,0); stB(0,1,0); stA(0,1,0); stA(0,3,0);
    stA(1,0,1); stA(1,2,1); stB(1,0,1); stB(1,1,1);
    asm volatile("s_waitcnt vmcnt(4)");
    __builtin_amdgcn_s_barrier();
    asm volatile("" ::: "memory");

    for (int i = 0; i < NI - 1; ++i) {
        const int t = 2 * i;
        // ---- buf0 (tile t) ----
        LDA4(0, 0, 0) LDBA(0)
        stA(1, 1, t + 1); stA(1, 3, t + 1);
        SYNC_HEAD
        OCT(0, 0)
        LDA4(0, 0, 1)
        SYNC_TAIL
        SYNC_HEAD
        OCT(0, 1)
        LDA4(0, 1, 0)
        SYNC_TAIL
        stA(0, 0, t + 2); stA(0, 2, t + 2);
        SYNC_HEAD
        OCT(1, 0)
        LDA4(0, 1, 1)
        SYNC_TAIL
        stB(0, 0, t + 2); stB(0, 1, t + 2);
        SYNC_HEAD
        OCT(1, 1)
        asm volatile("s_waitcnt vmcnt(4)");
        SYNC_TAIL
        // ---- buf1 (tile t+1) ----
        LDA4(1, 0, 0) LDBA(1)
        stA(0, 1, t + 2); stA(0, 3, t + 2);
        SYNC_HEAD
        OCT(0, 0)
        LDA4(1, 0, 1)
        SYNC_TAIL
        SYNC_HEAD
        OCT(0, 1)
        LDA4(1, 1, 0)
        SYNC_TAIL
        stA(1, 0, t + 3); stA(1, 2, t + 3);
        SYNC_HEAD
        OCT(1, 0)
        LDA4(1, 1, 1)
        SYNC_TAIL
        stB(1, 0, t + 3); stB(1, 1, t + 3);
        SYNC_HEAD
        OCT(1, 1)
        asm volatile("s_waitcnt vmcnt(4)");
        SYNC_TAIL
    }
    {   // final iteration
        LDA4(0, 0, 0) LDBA(0)
        stA(1, 1, NT - 1); stA(1, 3, NT - 1);
        SYNC_HEAD
        OCT(0, 0)
        LDA4(0, 0, 1)
        SYNC_TAIL
        SYNC_HEAD
        OCT(0, 1)
        LDA4(0, 1, 0)
        SYNC_TAIL
        SYNC_HEAD
        OCT(1, 0)
        LDA4(0, 1, 1)
        SYNC_TAIL
        SYNC_HEAD
        OCT(1, 1)
        asm volatile("s_waitcnt vmcnt(0)");
        SYNC_TAIL
        LDA4(1, 0, 0) LDBA(1)
        SYNC_HEAD
        OCT(0, 0)
        LDA4(1, 0, 1)
        SYNC_TAIL
        SYNC_HEAD
        OCT(0, 1)
        LDA4(1, 1, 0)
        SYNC_TAIL
        SYNC_HEAD
        OCT(1, 0)
        LDA4(1, 1, 1)
        SYNC_TAIL
        SYNC_HEAD
        OCT(1, 1)
        SYNC_TAIL
    }
#undef LDA4
#undef LDBA
#undef OCT

    const size_t row0 = bm + (size_t)wm * 128;
    const int col0 = (int)bn + wn * 32;
    const int c0 = lane & 15, r0 = (lane >> 4) * 4;
#pragma unroll
    for (int fm = 0; fm < 8; fm++)
#pragma unroll
        for (int r = 0; r < 4; r++) {
            const size_t row = row0 + fm * 16 + r0 + r;
            if constexpr (GN == 0) {
                const float g = gate[row * NE];
#pragma unroll
                for (int n = 0; n < 2; n++) {
                    const size_t col = (size_t)col0 + n * 16 + c0;
                    float v = (acc[fm][n][r] + bias[col]) * g;
                    float* p = Cptr + row * (size_t)N + col;
                    *p = ACCUM ? (*p + v) : v;
                }
            } else {
                float gv[GN];
#pragma unroll
                for (int j = 0; j < GN; j++) gv[j] = gate[row * NE + e0 + j];
#pragma unroll
                for (int n = 0; n < 2; n++) {
                    const size_t col = (size_t)col0 + n * 16 + c0;
                    float bb = 0.f;
#pragma unroll
                    for (int j = 0; j < GN; j++)
                        bb = fmaf(gv[j], bias[(size_t)(e0 + j) * N + col], bb);
                    float v = acc[fm][n][r] + bb;
                    float* p = Cptr + row * (size_t)N + col;
                    *p = ACCUM ? (*p + v) : v;
                }
            }
        }
}

// --------- gating head: logits = gh@gw2 + gb2, softmax -> gates fp32 -------
__global__ __launch_bounds__(256) void gate_softmax_kernel(
    const f16* __restrict__ gh, const float* __restrict__ gw2,
    const float* __restrict__ gb2, float* __restrict__ gates)
{
    const int row  = blockIdx.x * 4 + (threadIdx.x >> 6);
    const int lane = threadIdx.x & 63;
    const f16* r = gh + (size_t)row * HGD;
    float acc[NE] = {};
    for (int kb = lane * 8; kb < HGD; kb += 512) {
        f16x8 v = *(const f16x8*)(r + kb);
#pragma unroll
        for (int j = 0; j < 8; j++) {
            float h = (float)v[j];
            const float* w = gw2 + (size_t)(kb + j) * NE;
#pragma unroll
            for (int e = 0; e < NE; e++) acc[e] = fmaf(h, w[e], acc[e]);
        }
    }
#pragma unroll
    for (int off = 32; off > 0; off >>= 1)
#pragma unroll
        for (int e = 0; e < NE; e++) acc[e] += __shfl_down(acc[e], off, 64);
    if (lane == 0) {
        float l[NE], m = -1e30f;
#pragma unroll
        for (int e = 0; e < NE; e++) { l[e] = acc[e] + gb2[e]; m = fmaxf(m, l[e]); }
        float s = 0.f;
#pragma unroll
        for (int e = 0; e < NE; e++) { l[e] = expf(l[e] - m); s += l[e]; }
        float inv = 1.0f / s;
#pragma unroll
        for (int e = 0; e < NE; e++) gates[(size_t)row * NE + e] = l[e] * inv;
    }
}

// ---------------------------------------------------------------------------
extern "C" void kernel_launch(void* const* d_in, const int* in_sizes, int n_in,
                              void* d_out, int out_size, void* d_ws, size_t ws_size,
                              hipStream_t stream)
{
    const float* x   = (const float*)d_in[0];
    const float* gw1 = (const float*)d_in[1];
    const float* gb1 = (const float*)d_in[2];
    const float* gw2 = (const float*)d_in[3];
    const float* gb2 = (const float*)d_in[4];
    const float* ew1 = (const float*)d_in[5];
    const float* eb1 = (const float*)d_in[6];
    const float* ew2 = (const float*)d_in[7];
    const float* eb2 = (const float*)d_in[8];
    float* out = (float*)d_out;

    const size_t SZ_GATES = 256 << 10;
    const size_t SZ_X16   = (size_t)BSZ * IND * 2;
    const size_t SZ_WBUF  = (size_t)HID * IND * 2;
    const size_t SZ_W1ALL = (size_t)NE * HID * IND * 2;
    const size_t SZ_W2ALL = (size_t)NE * OUTD * HID * 2;
    const size_t SZ_HB1   = (size_t)BSZ * HID * 2;
    const size_t BASE     = SZ_GATES + SZ_X16 + SZ_W1ALL + SZ_W2ALL;
    const size_t NEED_G4  = BASE + 4 * SZ_HB1;
    const size_t NEED_G2  = BASE + 2 * SZ_HB1;
    const size_t NEED_G1  = BASE + 1 * SZ_HB1;

    char* p = (char*)d_ws;
    float* gates = (float*)p;  p += SZ_GATES;
    f16* x16 = (f16*)p;        p += SZ_X16;

    conv_f32_f16_kernel<<<(BSZ * IND) / (256 * 8), 256, 0, stream>>>(x, x16);

    if (ws_size >= NEED_G2) {
        const int G = (ws_size >= NEED_G4) ? 4 : 2;
        f16* w1all = (f16*)p;  p += SZ_W1ALL;
        f16* w2cat = (f16*)p;  p += SZ_W2ALL;
        f16* hbufG = (f16*)p;
        f16* gh    = hbufG;

        transpose_f32_f16_kernel<<<dim3(HGD / 64, IND / 64, 1), 256, 0, stream>>>(
            gw1, w1all, IND, HGD, IND, 0, 0);
        gemm256_kernel<true, false>
            <<<dim3((HGD / 256) * (BSZ / 256), 1, 1), 512, 0, stream>>>(
                x16, w1all, gb1, nullptr, gh, BSZ, HGD, IND, HGD, 0);
        gate_softmax_kernel<<<BSZ / 4, 256, 0, stream>>>(gh, gw2, gb2, gates);

        transpose_f32_f16_kernel<<<dim3(HID / 64, IND / 64, NE), 256, 0, stream>>>(
            ew1, w1all, IND, HID, IND, (size_t)HID * IND, 0);
        transpose_f32_f16_kernel<<<dim3(OUTD / 64, HID / 64, NE), 256, 0, stream>>>(
            ew2, w2cat, HID, OUTD, NE * HID, 0, HID);

        for (int g = 0; g < NE / G; g++) {
            gemm256_kernel<true, true>
                <<<dim3((HID / 256) * (BSZ / 256), 1, G), 512, 0, stream>>>(
                    x16, w1all + (size_t)g * G * HID * IND, eb1 + g * G * HID,
                    gates, hbufG, BSZ, HID, IND, G * HID, g * G);
            if (G == 4) {
                if (g == 0)
                    gemmO_kernel<false, 4>
                        <<<(OUTD / 128) * (BSZ / 256), 512, 0, stream>>>(
                            hbufG, w2cat + (size_t)g * G * HID, eb2, gates, out,
                            BSZ, OUTD, G * HID, NE * HID, g * G);
                else
                    gemmO_kernel<true, 4>
                        <<<(OUTD / 128) * (BSZ / 256), 512, 0, stream>>>(
                            hbufG, w2cat + (size_t)g * G * HID, eb2, gates, out,
                            BSZ, OUTD, G * HID, NE * HID, g * G);
            } else {
                if (g == 0)
                    gemmO_kernel<false, 2>
                        <<<(OUTD / 128) * (BSZ / 256), 512, 0, stream>>>(
                            hbufG, w2cat + (size_t)g * G * HID, eb2, gates, out,
                            BSZ, OUTD, G * HID, NE * HID, g * G);
                else
                    gemmO_kernel<true, 2>
                        <<<(OUTD / 128) * (BSZ / 256), 512, 0, stream>>>(
                            hbufG, w2cat + (size_t)g * G * HID, eb2, gates, out,
                            BSZ, OUTD, G * HID, NE * HID, g * G);
            }
        }
    } else if (ws_size >= NEED_G1) {
        f16* w1all = (f16*)p;  p += SZ_W1ALL;
        f16* w2all = (f16*)p;  p += SZ_W2ALL;
        f16* hbuf  = (f16*)p;
        f16* gh    = hbuf;

        transpose_f32_f16_kernel<<<dim3(HGD / 64, IND / 64, 1), 256, 0, stream>>>(
            gw1, w1all, IND, HGD, IND, 0, 0);
        gemm256_kernel<true, false>
            <<<dim3((HGD / 256) * (BSZ / 256), 1, 1), 512, 0, stream>>>(
                x16, w1all, gb1, nullptr, gh, BSZ, HGD, IND, HGD, 0);
        gate_softmax_kernel<<<BSZ / 4, 256, 0, stream>>>(gh, gw2, gb2, gates);

        transpose_f32_f16_kernel<<<dim3(HID / 64, IND / 64, NE), 256, 0, stream>>>(
            ew1, w1all, IND, HID, IND, (size_t)HID * IND, 0);
        transpose_f32_f16_kernel<<<dim3(OUTD / 64, HID / 64, NE), 256, 0, stream>>>(
            ew2, w2all, HID, OUTD, HID, (size_t)OUTD * HID, 0);

        for (int e = 0; e < NE; e++) {
            gemm256_kernel<true, false>
                <<<dim3((HID / 256) * (BSZ / 256), 1, 1), 512, 0, stream>>>(
                    x16, w1all + (size_t)e * HID * IND, eb1 + (size_t)e * HID,
                    nullptr, hbuf, BSZ, HID, IND, HID, 0);
            if (e == 0)
                gemmO_kernel<false, 0><<<(OUTD / 128) * (BSZ / 256), 512, 0, stream>>>(
                    hbuf, w2all + (size_t)e * OUTD * HID, eb2 + (size_t)e * OUTD,
                    gates + e, out, BSZ, OUTD, HID, HID, 0);
            else
                gemmO_kernel<true, 0><<<(OUTD / 128) * (BSZ / 256), 512, 0, stream>>>(
                    hbuf, w2all + (size_t)e * OUTD * HID, eb2 + (size_t)e * OUTD,
                    gates + e, out, BSZ, OUTD, HID, HID, 0);
        }
    } else {
        f16* wbuf = (f16*)p;   p += SZ_WBUF;
        f16* hbuf = (f16*)p;
        f16* gh   = hbuf;

        transpose_f32_f16_kernel<<<dim3(HGD / 64, IND / 64, 1), 256, 0, stream>>>(
            gw1, wbuf, IND, HGD, IND, 0, 0);
        gemm256_kernel<true, false>
            <<<dim3((HGD / 256) * (BSZ / 256), 1, 1), 512, 0, stream>>>(
                x16, wbuf, gb1, nullptr, gh, BSZ, HGD, IND, HGD, 0);
        gate_softmax_kernel<<<BSZ / 4, 256, 0, stream>>>(gh, gw2, gb2, gates);

        for (int e = 0; e < NE; e++) {
            transpose_f32_f16_kernel<<<dim3(HID / 64, IND / 64, 1), 256, 0, stream>>>(
                ew1 + (size_t)e * IND * HID, wbuf, IND, HID, IND, 0, 0);
            gemm256_kernel<true, false>
                <<<dim3((HID / 256) * (BSZ / 256), 1, 1), 512, 0, stream>>>(
                    x16, wbuf, eb1 + (size_t)e * HID, nullptr, hbuf,
                    BSZ, HID, IND, HID, 0);

            transpose_f32_f16_kernel<<<dim3(OUTD / 64, HID / 64, 1), 256, 0, stream>>>(
                ew2 + (size_t)e * HID * OUTD, wbuf, HID, OUTD, HID, 0, 0);
            if (e == 0)
                gemmO_kernel<false, 0><<<(OUTD / 128) * (BSZ / 256), 512, 0, stream>>>(
                    hbuf, wbuf, eb2 + (size_t)e * OUTD, gates + e, out,
                    BSZ, OUTD, HID, HID, 0);
            else
                gemmO_kernel<true, 0><<<(OUTD / 128) * (BSZ / 256), 512, 0, stream>>>(
                    hbuf, wbuf, eb2 + (size_t)e * OUTD, gates + e, out,
                    BSZ, OUTD, HID, HID, 0);
        }
    }
}